// Round 1
// 615.442 us; speedup vs baseline: 1.0995x; 1.0995x over previous
//
#include <hip/hip_runtime.h>

// APPNP-style propagation: 4 hops of M = 0.9*A_hat + 0.1*I on x[N,128], y[N,32].
// Round 8:
//  passA rewritten as WG-aggregated counting sort:
//   - old: per-edge returning atomicAdd on bucket counter + scattered 4B store
//     -> 1.6M returning atomics, 89 MB write amplification, 134.6 us.
//   - new: per-WG 4096-edge chunk; LDS histogram (391 buckets) -> LDS scan ->
//     ONE returning global atomic per (WG,bucket) on a line-padded counter
//     (~153K returning atomics) -> LDS counting sort -> contiguous per-bucket
//     burst writes (L2 line-merged).
//  indeg atomics stay per-edge, replicated by REAL XCD id (fire-and-forget).
//  passB simplified: single bucket buffer (no 8 replicas), 22 KB LDS.

#define NN 100000
#define EE 1600000
#define NPAD 100096     // N padded to multiple of 64
#define NBKT 391        // ceil(NN/256); bucket = src >> 8
#define CHUNK 4096      // edges per passA workgroup
#define CAP2 5120       // per-bucket capacity: mean 4092 + 16 sigma

#define GETREG_XCC_IMM (((32 - 1) << 11) | (0 << 6) | 20)   // HW_REG_XCC_ID, full width

// ---------- bf16 helpers (RNE) ----------
__device__ __forceinline__ float bflo(unsigned w) { return __uint_as_float(w << 16); }
__device__ __forceinline__ float bfhi(unsigned w) { return __uint_as_float(w & 0xffff0000u); }
__device__ __forceinline__ unsigned packbf(float a, float b) {
    unsigned ua = __float_as_uint(a), ub = __float_as_uint(b);
    unsigned ra = (ua + 0x7fffu + ((ua >> 16) & 1u)) >> 16;
    unsigned rb = (ub + 0x7fffu + ((ub >> 16) & 1u)) >> 16;
    return ra | (rb << 16);
}

// ---------- preprocessing ----------

__global__ void detect_kernel(const int* __restrict__ raw, int* __restrict__ flag) {
    if (threadIdx.x == 0 && blockIdx.x == 0) {
        int is64 = 1;
        for (int k = 1; k < 16; k += 2) {
            if (raw[k] != 0) { is64 = 0; break; }
        }
        *flag = is64;
    }
}

__global__ void zero_kernel(int* __restrict__ bufs, int total) {
    int i = blockIdx.x * blockDim.x + threadIdx.x;
    if (i < total) bufs[i] = 0;
}

// WG-aggregated bucket sort over a 4096-edge chunk.
// gbcur counters are strided by 16 ints (one 64B line each) to avoid
// cross-XCD same-line atomic serialization.
__global__ __launch_bounds__(256) void passA_kernel(const void* __restrict__ raw,
                                                    const int* __restrict__ flag,
                                                    int* __restrict__ indeg_rep,
                                                    int* __restrict__ gbcur,
                                                    int* __restrict__ buf) {
    __shared__ unsigned short sh_b[CHUNK];      // bucket per original slot   (8 KB)
    __shared__ unsigned int   sh_p[CHUNK];      // packed (s&255)<<17 | d     (16 KB)
    __shared__ unsigned int   sh_sorted[CHUNK]; // bucket-ordered packed      (16 KB)
    __shared__ unsigned short sh_bs[CHUNK];     // bucket per sorted slot     (8 KB)
    __shared__ int hist[512];
    __shared__ int excl[512];
    __shared__ int gbase[512];
    __shared__ int lcur[512];                   // 4 x 2 KB = 8 KB; total 56 KB

    int tid = threadIdx.x;
    int base = blockIdx.x * CHUNK;
    int nval = EE - base; if (nval > CHUNK) nval = CHUNK;
    int r = __builtin_amdgcn_s_getreg(GETREG_XCC_IMM) & 7;   // wave-uniform XCD id
    int is64 = *flag;

    hist[tid] = 0; hist[tid + 256] = 0;
    __syncthreads();

    // load edges, indeg atomic (fire-and-forget), LDS bucket histogram
    for (int i = tid; i < nval; i += 256) {
        int e = base + i;
        int s, d;
        if (is64) {
            s = (int)((const long long*)raw)[e];
            d = (int)((const long long*)raw)[EE + e];
        } else {
            s = ((const int*)raw)[e];
            d = ((const int*)raw)[EE + e];
        }
        atomicAdd(&indeg_rep[r * NPAD + d], 1);
        int b = s >> 8;
        sh_b[i] = (unsigned short)b;
        sh_p[i] = ((unsigned)(s & 255) << 17) | (unsigned)d;
        atomicAdd(&hist[b], 1);
    }
    __syncthreads();

    // inclusive Hillis-Steele scan of hist (512 entries, 256 threads)
    excl[tid] = hist[tid];
    excl[tid + 256] = hist[tid + 256];
    __syncthreads();
    for (int off = 1; off < 512; off <<= 1) {
        int a0 = (tid >= off) ? excl[tid - off] : 0;
        int a1 = (tid + 256 >= off) ? excl[tid + 256 - off] : 0;
        __syncthreads();
        excl[tid] += a0;
        excl[tid + 256] += a1;
        __syncthreads();
    }
    // exclusive prefix + per-bucket global reservation (one returning atomic
    // per nonempty (WG,bucket))
    int inc0 = excl[tid], inc1 = excl[tid + 256];
    int h0 = hist[tid],  h1 = hist[tid + 256];
    __syncthreads();
    int e0 = inc0 - h0, e1 = inc1 - h1;
    excl[tid] = e0; excl[tid + 256] = e1;
    lcur[tid] = e0; lcur[tid + 256] = e1;
    if (h0 > 0) gbase[tid]       = atomicAdd(&gbcur[tid * 16], h0);
    if (h1 > 0) gbase[tid + 256] = atomicAdd(&gbcur[(tid + 256) * 16], h1);
    __syncthreads();

    // LDS counting sort: place each edge into its bucket run
    for (int i = tid; i < nval; i += 256) {
        int b = sh_b[i];
        int pos = atomicAdd(&lcur[b], 1);
        sh_sorted[pos] = sh_p[i];
        sh_bs[pos] = (unsigned short)b;
    }
    __syncthreads();

    // stream out: consecutive sorted slots -> consecutive global addresses
    // within each bucket run (bursts ~ nval/NBKT edges -> L2 line-merged)
    for (int i = tid; i < nval; i += 256) {
        int b = sh_bs[i];
        int gpos = gbase[b] + (i - excl[b]);
        if (gpos < CAP2)
            buf[(size_t)b * CAP2 + gpos] = (int)sh_sorted[i];
    }
}

// Exclusive prefix over bucket totals -> bucket_base; set rowptr[NN]=EE.
__global__ void bucket_scan_kernel(const int* __restrict__ gbcur, int* __restrict__ bucket_base,
                                   int* __restrict__ rowptr) {
    __shared__ int s[512];
    int tid = threadIdx.x;
    int v = 0;
    if (tid < NBKT) {
        int c = gbcur[tid * 16];
        v = (c < CAP2) ? c : CAP2;
    }
    s[tid] = v;
    __syncthreads();
    for (int off = 1; off < 512; off <<= 1) {
        int t = (tid >= off) ? s[tid - off] : 0;
        __syncthreads();
        s[tid] += t;
        __syncthreads();
    }
    if (tid < NBKT) bucket_base[tid] = s[tid] - v;
    if (tid == 0) rowptr[NN] = EE;
}

__global__ void dinv_kernel(const int* __restrict__ indeg_rep, float* __restrict__ dinv) {
    int i = blockIdx.x * blockDim.x + threadIdx.x;
    if (i < NN) {
        int ind = 1;
        #pragma unroll
        for (int r = 0; r < 8; ++r) ind += indeg_rep[r * NPAD + i];
        dinv[i] = rsqrtf((float)ind);
    }
}

// Cast fp32 inputs to pre-scaled bf16: zx[i] = dinv[i]*x0[i], zy[i] = dinv[i]*y0[i].
__global__ void cast_kernel(const float4* __restrict__ x0, const float4* __restrict__ y0,
                            const float* __restrict__ dinv, uint4* __restrict__ zx,
                            uint4* __restrict__ zy) {
    int t = blockIdx.x * blockDim.x + threadIdx.x;
    if (t < NN * 16) {
        int node = t >> 4, c = t & 15;
        float di = dinv[node];
        float4 a = x0[(size_t)node * 32 + c * 2];
        float4 b = x0[(size_t)node * 32 + c * 2 + 1];
        uint4 o;
        o.x = packbf(di * a.x, di * a.y); o.y = packbf(di * a.z, di * a.w);
        o.z = packbf(di * b.x, di * b.y); o.w = packbf(di * b.z, di * b.w);
        zx[(size_t)node * 16 + c] = o;
    } else if (t < NN * 20) {
        int u = t - NN * 16;
        int node = u >> 2, c = u & 3;
        float di = dinv[node];
        float4 a = y0[(size_t)node * 8 + c * 2];
        float4 b = y0[(size_t)node * 8 + c * 2 + 1];
        uint4 o;
        o.x = packbf(di * a.x, di * a.y); o.y = packbf(di * a.z, di * a.w);
        o.z = packbf(di * b.x, di * b.y); o.w = packbf(di * b.z, di * b.w);
        zy[(size_t)node * 4 + c] = o;
    }
}

// One WG per bucket: stage run + histogram -> scan -> rowptr + contiguous dst slice.
__global__ __launch_bounds__(256) void passB_kernel(const int* __restrict__ gbcur,
                                                    const int* __restrict__ buf,
                                                    const int* __restrict__ bucket_base,
                                                    int* __restrict__ rowptr,
                                                    int* __restrict__ dst_sorted) {
    int b = blockIdx.x;
    int tid = threadIdx.x;
    __shared__ int edges[CAP2];      // 20 KB
    __shared__ int hist[256];
    __shared__ int sc[256];
    __shared__ int base_s, tot_s;

    if (tid == 0) {
        int c = gbcur[b * 16];
        tot_s = (c < CAP2) ? c : CAP2;
        base_s = bucket_base[b];
    }
    hist[tid] = 0;
    __syncthreads();
    int total = tot_s;
    const int* src = buf + (size_t)b * CAP2;
    for (int i = tid; i < total; i += 256) {
        int p = src[i];
        edges[i] = p;
        atomicAdd(&hist[p >> 17], 1);
    }
    __syncthreads();
    int hv = hist[tid];
    sc[tid] = hv;
    __syncthreads();
    for (int o = 1; o < 256; o <<= 1) {
        int t = (tid >= o) ? sc[tid - o] : 0;
        __syncthreads();
        sc[tid] += t;
        __syncthreads();
    }
    int excl = sc[tid] - hv;
    int node = (b << 8) + tid;
    if (node < NN) rowptr[node] = base_s + excl;
    hist[tid] = excl;
    __syncthreads();
    for (int i = tid; i < total; i += 256) {
        int p = edges[i];
        int pos = atomicAdd(&hist[p >> 17], 1);
        dst_sorted[base_s + pos] = p & 0x1ffff;
    }
}

// ---------- fused per-hop kernel ----------
// Iterates stored pre-scaled: z = dinv*u (bf16). Per row:
//   u'_row = 0.9*di*sum_e z[d_e] + (0.9*di + 0.1/di)*z_row ; store z' = di*u' (or u' fp32).
template <bool OUTBF>
__global__ __launch_bounds__(256) void hop_kernel(const int* __restrict__ rowptr,
                                                  const int* __restrict__ dst_sorted,
                                                  const float* __restrict__ dinv,
                                                  const uint4* __restrict__ zx,
                                                  const uint4* __restrict__ zy,
                                                  void* __restrict__ nx,
                                                  void* __restrict__ ny) {
    int t = blockIdx.x * blockDim.x + threadIdx.x;
    int row = t >> 6, lane = t & 63;
    if (row >= NN) return;
    int beg = rowptr[row], end = rowptr[row + 1];

    // ---- x: 4 subgroups of 16 lanes, each lane owns 8 columns ----
    int g = lane >> 4, sub = lane & 15;
    float ax[8] = {0.f, 0.f, 0.f, 0.f, 0.f, 0.f, 0.f, 0.f};
    for (int e = beg + g; e < end; e += 4) {
        int d = dst_sorted[e];
        uint4 w = zx[(size_t)d * 16 + sub];
        ax[0] += bflo(w.x); ax[1] += bfhi(w.x);
        ax[2] += bflo(w.y); ax[3] += bfhi(w.y);
        ax[4] += bflo(w.z); ax[5] += bfhi(w.z);
        ax[6] += bflo(w.w); ax[7] += bfhi(w.w);
    }
    #pragma unroll
    for (int m = 16; m <= 32; m <<= 1) {
        #pragma unroll
        for (int i = 0; i < 8; ++i) ax[i] += __shfl_xor(ax[i], m);
    }

    // ---- y: 16 subgroups of 4 lanes, each lane owns 8 columns ----
    int gy = lane >> 2, sy = lane & 3;
    float ay[8] = {0.f, 0.f, 0.f, 0.f, 0.f, 0.f, 0.f, 0.f};
    for (int e = beg + gy; e < end; e += 16) {
        int d = dst_sorted[e];
        uint4 w = zy[(size_t)d * 4 + sy];
        ay[0] += bflo(w.x); ay[1] += bfhi(w.x);
        ay[2] += bflo(w.y); ay[3] += bfhi(w.y);
        ay[4] += bflo(w.z); ay[5] += bfhi(w.z);
        ay[6] += bflo(w.w); ay[7] += bfhi(w.w);
    }
    #pragma unroll
    for (int m = 4; m <= 32; m <<= 1) {
        #pragma unroll
        for (int i = 0; i < 8; ++i) ay[i] += __shfl_xor(ay[i], m);
    }

    float di = dinv[row];
    float sg = 0.9f * di;
    float sl = 0.9f * di + 0.1f / di;   // coefficient on z_row giving the u-space self term

    if (g == 0) {   // lanes 0..15 write x
        uint4 wz = zx[(size_t)row * 16 + sub];
        float c[8] = { bflo(wz.x), bfhi(wz.x), bflo(wz.y), bfhi(wz.y),
                       bflo(wz.z), bfhi(wz.z), bflo(wz.w), bfhi(wz.w) };
        float r[8];
        #pragma unroll
        for (int i = 0; i < 8; ++i) r[i] = sg * ax[i] + sl * c[i];   // u'
        if constexpr (OUTBF) {
            uint4 o;
            o.x = packbf(di * r[0], di * r[1]); o.y = packbf(di * r[2], di * r[3]);
            o.z = packbf(di * r[4], di * r[5]); o.w = packbf(di * r[6], di * r[7]);
            ((uint4*)nx)[(size_t)row * 16 + sub] = o;
        } else {
            float4 a, b;
            a.x = r[0]; a.y = r[1]; a.z = r[2]; a.w = r[3];
            b.x = r[4]; b.y = r[5]; b.z = r[6]; b.w = r[7];
            ((float4*)nx)[(size_t)row * 32 + sub * 2]     = a;
            ((float4*)nx)[(size_t)row * 32 + sub * 2 + 1] = b;
        }
    }
    if (gy == 0) {  // lanes 0..3 write y
        uint4 wz = zy[(size_t)row * 4 + sy];
        float c[8] = { bflo(wz.x), bfhi(wz.x), bflo(wz.y), bfhi(wz.y),
                       bflo(wz.z), bfhi(wz.z), bflo(wz.w), bfhi(wz.w) };
        float r[8];
        #pragma unroll
        for (int i = 0; i < 8; ++i) r[i] = sg * ay[i] + sl * c[i];
        if constexpr (OUTBF) {
            uint4 o;
            o.x = packbf(di * r[0], di * r[1]); o.y = packbf(di * r[2], di * r[3]);
            o.z = packbf(di * r[4], di * r[5]); o.w = packbf(di * r[6], di * r[7]);
            ((uint4*)ny)[(size_t)row * 4 + sy] = o;
        } else {
            float4 a, b;
            a.x = r[0]; a.y = r[1]; a.z = r[2]; a.w = r[3];
            b.x = r[4]; b.y = r[5]; b.z = r[6]; b.w = r[7];
            ((float4*)ny)[(size_t)row * 8 + sy * 2]     = a;
            ((float4*)ny)[(size_t)row * 8 + sy * 2 + 1] = b;
        }
    }
}

extern "C" void kernel_launch(void* const* d_in, const int* in_sizes, int n_in,
                              void* d_out, int out_size, void* d_ws, size_t ws_size,
                              hipStream_t stream) {
    const float* x0  = (const float*)d_in[0];
    const float* y0  = (const float*)d_in[1];
    const void*  raw = d_in[2];

    float* out_x = (float*)d_out;
    float* out_y = out_x + (size_t)NN * 128;

    // ws layout (4-byte words):
    // flag[16] | indeg_rep[8*NPAD] | gbcur[512*16] | bucket_base[512] | rowptr[100112]
    // | dinv[NPAD] | buf[NBKT*CAP2] | dst_sorted[EE] | zxA[N*64] | zxB[N*64]
    // | zyA[N*16] | zyB[N*16]   ~= 78 MB
    int*   flag        = (int*)d_ws;
    int*   indeg_rep   = flag + 16;
    int*   gbcur       = indeg_rep + 8 * NPAD;
    int*   bucket_base = gbcur + 512 * 16;
    int*   rowptr      = bucket_base + 512;
    float* dinv        = (float*)(rowptr + 100112);
    int*   buf         = (int*)(dinv + NPAD);
    int*   dst_sorted  = buf + (size_t)NBKT * CAP2;
    uint4* zxA         = (uint4*)(dst_sorted + EE);
    uint4* zxB         = zxA + (size_t)NN * 16;
    uint4* zyA         = (uint4*)(zxB + (size_t)NN * 16);
    uint4* zyB         = zyA + (size_t)NN * 4;

    const int B = 256;
    const int GW = (NN * 64 + B - 1) / B;   // one wave per row
    const int ZTOT = 8 * NPAD + 512 * 16;

    detect_kernel<<<1, 64, 0, stream>>>((const int*)raw, flag);
    zero_kernel<<<(ZTOT + B - 1) / B, B, 0, stream>>>(indeg_rep, ZTOT);
    passA_kernel<<<(EE + CHUNK - 1) / CHUNK, 256, 0, stream>>>(raw, flag, indeg_rep, gbcur, buf);
    bucket_scan_kernel<<<1, 512, 0, stream>>>(gbcur, bucket_base, rowptr);
    dinv_kernel<<<(NN + B - 1) / B, B, 0, stream>>>(indeg_rep, dinv);
    cast_kernel<<<(NN * 20 + B - 1) / B, B, 0, stream>>>(
        (const float4*)x0, (const float4*)y0, dinv, zxA, zyA);
    passB_kernel<<<NBKT, 256, 0, stream>>>(gbcur, buf, bucket_base, rowptr, dst_sorted);

    // hops 1-3: bf16 z -> bf16 z ; hop 4: bf16 z -> fp32 u (d_out)
    hop_kernel<true><<<GW, B, 0, stream>>>(rowptr, dst_sorted, dinv, zxA, zyA, zxB, zyB);
    hop_kernel<true><<<GW, B, 0, stream>>>(rowptr, dst_sorted, dinv, zxB, zyB, zxA, zyA);
    hop_kernel<true><<<GW, B, 0, stream>>>(rowptr, dst_sorted, dinv, zxA, zyA, zxB, zyB);
    hop_kernel<false><<<GW, B, 0, stream>>>(rowptr, dst_sorted, dinv, zxB, zyB, out_x, out_y);
}

// Round 2
// 591.729 us; speedup vs baseline: 1.1436x; 1.0401x over previous
//
#include <hip/hip_runtime.h>

// APPNP-style propagation: 4 hops of M = 0.9*A_hat + 0.1*I on x[N,128], y[N,32].
// Round 9:
//  hop_kernel restructured for memory-level parallelism (was latency-bound:
//  VALUBusy 42%, hbm 43%, occupancy 75% -> no pipe saturated).
//   - old: serial x-loop (avg 4 dependent gather rounds) then serial y-loop (1 round).
//   - new: single merged loop over 16-edge batches; per batch 5 INDEPENDENT
//     16B gathers (4 x-subgroup loads + 1 y load) issued back-to-back.
//     Out-of-range slots: index clamped to end-1 (valid addr) and contribution
//     multiplied by 0/1 mask (add->fma, branch-free). Avg memory rounds per
//     row: ~5 -> ~1.4, each with 5-deep MLP.
//  passA (R8): WG-aggregated counting sort, LDS histogram + per-(WG,bucket)
//  reservation; indeg atomics XCD-replicated via s_getreg(HW_REG_XCC_ID).

#define NN 100000
#define EE 1600000
#define NPAD 100096     // N padded to multiple of 64
#define NBKT 391        // ceil(NN/256); bucket = src >> 8
#define CHUNK 4096      // edges per passA workgroup
#define CAP2 5120       // per-bucket capacity: mean 4092 + 16 sigma

#define GETREG_XCC_IMM (((32 - 1) << 11) | (0 << 6) | 20)   // HW_REG_XCC_ID, full width

// ---------- bf16 helpers (RNE) ----------
__device__ __forceinline__ float bflo(unsigned w) { return __uint_as_float(w << 16); }
__device__ __forceinline__ float bfhi(unsigned w) { return __uint_as_float(w & 0xffff0000u); }
__device__ __forceinline__ unsigned packbf(float a, float b) {
    unsigned ua = __float_as_uint(a), ub = __float_as_uint(b);
    unsigned ra = (ua + 0x7fffu + ((ua >> 16) & 1u)) >> 16;
    unsigned rb = (ub + 0x7fffu + ((ub >> 16) & 1u)) >> 16;
    return ra | (rb << 16);
}

// ---------- preprocessing ----------

__global__ void detect_kernel(const int* __restrict__ raw, int* __restrict__ flag) {
    if (threadIdx.x == 0 && blockIdx.x == 0) {
        int is64 = 1;
        for (int k = 1; k < 16; k += 2) {
            if (raw[k] != 0) { is64 = 0; break; }
        }
        *flag = is64;
    }
}

__global__ void zero_kernel(int* __restrict__ bufs, int total) {
    int i = blockIdx.x * blockDim.x + threadIdx.x;
    if (i < total) bufs[i] = 0;
}

// WG-aggregated bucket sort over a 4096-edge chunk.
__global__ __launch_bounds__(256) void passA_kernel(const void* __restrict__ raw,
                                                    const int* __restrict__ flag,
                                                    int* __restrict__ indeg_rep,
                                                    int* __restrict__ gbcur,
                                                    int* __restrict__ buf) {
    __shared__ unsigned short sh_b[CHUNK];      // bucket per original slot   (8 KB)
    __shared__ unsigned int   sh_p[CHUNK];      // packed (s&255)<<17 | d     (16 KB)
    __shared__ unsigned int   sh_sorted[CHUNK]; // bucket-ordered packed      (16 KB)
    __shared__ unsigned short sh_bs[CHUNK];     // bucket per sorted slot     (8 KB)
    __shared__ int hist[512];
    __shared__ int excl[512];
    __shared__ int gbase[512];
    __shared__ int lcur[512];                   // total 56 KB

    int tid = threadIdx.x;
    int base = blockIdx.x * CHUNK;
    int nval = EE - base; if (nval > CHUNK) nval = CHUNK;
    int r = __builtin_amdgcn_s_getreg(GETREG_XCC_IMM) & 7;   // wave-uniform XCD id
    int is64 = *flag;

    hist[tid] = 0; hist[tid + 256] = 0;
    __syncthreads();

    // load edges, indeg atomic (fire-and-forget), LDS bucket histogram
    for (int i = tid; i < nval; i += 256) {
        int e = base + i;
        int s, d;
        if (is64) {
            s = (int)((const long long*)raw)[e];
            d = (int)((const long long*)raw)[EE + e];
        } else {
            s = ((const int*)raw)[e];
            d = ((const int*)raw)[EE + e];
        }
        atomicAdd(&indeg_rep[r * NPAD + d], 1);
        int b = s >> 8;
        sh_b[i] = (unsigned short)b;
        sh_p[i] = ((unsigned)(s & 255) << 17) | (unsigned)d;
        atomicAdd(&hist[b], 1);
    }
    __syncthreads();

    // inclusive Hillis-Steele scan of hist (512 entries, 256 threads)
    excl[tid] = hist[tid];
    excl[tid + 256] = hist[tid + 256];
    __syncthreads();
    for (int off = 1; off < 512; off <<= 1) {
        int a0 = (tid >= off) ? excl[tid - off] : 0;
        int a1 = (tid + 256 >= off) ? excl[tid + 256 - off] : 0;
        __syncthreads();
        excl[tid] += a0;
        excl[tid + 256] += a1;
        __syncthreads();
    }
    // exclusive prefix + per-bucket global reservation
    int inc0 = excl[tid], inc1 = excl[tid + 256];
    int h0 = hist[tid],  h1 = hist[tid + 256];
    __syncthreads();
    int e0 = inc0 - h0, e1 = inc1 - h1;
    excl[tid] = e0; excl[tid + 256] = e1;
    lcur[tid] = e0; lcur[tid + 256] = e1;
    if (h0 > 0) gbase[tid]       = atomicAdd(&gbcur[tid * 16], h0);
    if (h1 > 0) gbase[tid + 256] = atomicAdd(&gbcur[(tid + 256) * 16], h1);
    __syncthreads();

    // LDS counting sort: place each edge into its bucket run
    for (int i = tid; i < nval; i += 256) {
        int b = sh_b[i];
        int pos = atomicAdd(&lcur[b], 1);
        sh_sorted[pos] = sh_p[i];
        sh_bs[pos] = (unsigned short)b;
    }
    __syncthreads();

    // stream out: consecutive sorted slots -> consecutive global addresses
    for (int i = tid; i < nval; i += 256) {
        int b = sh_bs[i];
        int gpos = gbase[b] + (i - excl[b]);
        if (gpos < CAP2)
            buf[(size_t)b * CAP2 + gpos] = (int)sh_sorted[i];
    }
}

// Exclusive prefix over bucket totals -> bucket_base; set rowptr[NN]=EE.
__global__ void bucket_scan_kernel(const int* __restrict__ gbcur, int* __restrict__ bucket_base,
                                   int* __restrict__ rowptr) {
    __shared__ int s[512];
    int tid = threadIdx.x;
    int v = 0;
    if (tid < NBKT) {
        int c = gbcur[tid * 16];
        v = (c < CAP2) ? c : CAP2;
    }
    s[tid] = v;
    __syncthreads();
    for (int off = 1; off < 512; off <<= 1) {
        int t = (tid >= off) ? s[tid - off] : 0;
        __syncthreads();
        s[tid] += t;
        __syncthreads();
    }
    if (tid < NBKT) bucket_base[tid] = s[tid] - v;
    if (tid == 0) rowptr[NN] = EE;
}

__global__ void dinv_kernel(const int* __restrict__ indeg_rep, float* __restrict__ dinv) {
    int i = blockIdx.x * blockDim.x + threadIdx.x;
    if (i < NN) {
        int ind = 1;
        #pragma unroll
        for (int r = 0; r < 8; ++r) ind += indeg_rep[r * NPAD + i];
        dinv[i] = rsqrtf((float)ind);
    }
}

// Cast fp32 inputs to pre-scaled bf16: zx[i] = dinv[i]*x0[i], zy[i] = dinv[i]*y0[i].
__global__ void cast_kernel(const float4* __restrict__ x0, const float4* __restrict__ y0,
                            const float* __restrict__ dinv, uint4* __restrict__ zx,
                            uint4* __restrict__ zy) {
    int t = blockIdx.x * blockDim.x + threadIdx.x;
    if (t < NN * 16) {
        int node = t >> 4, c = t & 15;
        float di = dinv[node];
        float4 a = x0[(size_t)node * 32 + c * 2];
        float4 b = x0[(size_t)node * 32 + c * 2 + 1];
        uint4 o;
        o.x = packbf(di * a.x, di * a.y); o.y = packbf(di * a.z, di * a.w);
        o.z = packbf(di * b.x, di * b.y); o.w = packbf(di * b.z, di * b.w);
        zx[(size_t)node * 16 + c] = o;
    } else if (t < NN * 20) {
        int u = t - NN * 16;
        int node = u >> 2, c = u & 3;
        float di = dinv[node];
        float4 a = y0[(size_t)node * 8 + c * 2];
        float4 b = y0[(size_t)node * 8 + c * 2 + 1];
        uint4 o;
        o.x = packbf(di * a.x, di * a.y); o.y = packbf(di * a.z, di * a.w);
        o.z = packbf(di * b.x, di * b.y); o.w = packbf(di * b.z, di * b.w);
        zy[(size_t)node * 4 + c] = o;
    }
}

// One WG per bucket: stage run + histogram -> scan -> rowptr + contiguous dst slice.
__global__ __launch_bounds__(256) void passB_kernel(const int* __restrict__ gbcur,
                                                    const int* __restrict__ buf,
                                                    const int* __restrict__ bucket_base,
                                                    int* __restrict__ rowptr,
                                                    int* __restrict__ dst_sorted) {
    int b = blockIdx.x;
    int tid = threadIdx.x;
    __shared__ int edges[CAP2];      // 20 KB
    __shared__ int hist[256];
    __shared__ int sc[256];
    __shared__ int base_s, tot_s;

    if (tid == 0) {
        int c = gbcur[b * 16];
        tot_s = (c < CAP2) ? c : CAP2;
        base_s = bucket_base[b];
    }
    hist[tid] = 0;
    __syncthreads();
    int total = tot_s;
    const int* src = buf + (size_t)b * CAP2;
    for (int i = tid; i < total; i += 256) {
        int p = src[i];
        edges[i] = p;
        atomicAdd(&hist[p >> 17], 1);
    }
    __syncthreads();
    int hv = hist[tid];
    sc[tid] = hv;
    __syncthreads();
    for (int o = 1; o < 256; o <<= 1) {
        int t = (tid >= o) ? sc[tid - o] : 0;
        __syncthreads();
        sc[tid] += t;
        __syncthreads();
    }
    int excl = sc[tid] - hv;
    int node = (b << 8) + tid;
    if (node < NN) rowptr[node] = base_s + excl;
    hist[tid] = excl;
    __syncthreads();
    for (int i = tid; i < total; i += 256) {
        int p = edges[i];
        int pos = atomicAdd(&hist[p >> 17], 1);
        dst_sorted[base_s + pos] = p & 0x1ffff;
    }
}

// ---------- fused per-hop kernel ----------
// Iterates stored pre-scaled: z = dinv*u (bf16). Per row:
//   u'_row = 0.9*di*sum_e z[d_e] + (0.9*di + 0.1/di)*z_row ; store z' = di*u' (or u' fp32).
// Merged 16-edge-batch loop: 5 independent gathers per iteration (MLP=5).
template <bool OUTBF>
__global__ __launch_bounds__(256) void hop_kernel(const int* __restrict__ rowptr,
                                                  const int* __restrict__ dst_sorted,
                                                  const float* __restrict__ dinv,
                                                  const uint4* __restrict__ zx,
                                                  const uint4* __restrict__ zy,
                                                  void* __restrict__ nx,
                                                  void* __restrict__ ny) {
    int t = blockIdx.x * blockDim.x + threadIdx.x;
    int row = t >> 6, lane = t & 63;
    if (row >= NN) return;
    int beg = rowptr[row], end = rowptr[row + 1];
    float di = dinv[row];

    int g = lane >> 4, sub = lane & 15;    // x: 4 edge-groups x 16 lanes
    int gy = lane >> 2, sy = lane & 3;     // y: 16 edge-groups x 4 lanes

    float ax[8] = {0.f, 0.f, 0.f, 0.f, 0.f, 0.f, 0.f, 0.f};
    float ay[8] = {0.f, 0.f, 0.f, 0.f, 0.f, 0.f, 0.f, 0.f};

    int last = end - 1;
    for (int e0 = beg; e0 < end; e0 += 16) {
        int ex0 = e0 + g, ex1 = e0 + 4 + g, ex2 = e0 + 8 + g, ex3 = e0 + 12 + g;
        int ey = e0 + gy;
        // clamped indices -> always-valid addresses; contribution masked by 0/1
        int d0 = dst_sorted[min(ex0, last)];
        int d1 = dst_sorted[min(ex1, last)];
        int d2 = dst_sorted[min(ex2, last)];
        int d3 = dst_sorted[min(ex3, last)];
        int dy = dst_sorted[min(ey, last)];
        // 5 independent 16B gathers, all in flight together
        uint4 w0 = zx[(size_t)d0 * 16 + sub];
        uint4 w1 = zx[(size_t)d1 * 16 + sub];
        uint4 w2 = zx[(size_t)d2 * 16 + sub];
        uint4 w3 = zx[(size_t)d3 * 16 + sub];
        uint4 wy = zy[(size_t)dy * 4 + sy];
        float m0 = (ex0 <= last) ? 1.f : 0.f;
        float m1 = (ex1 <= last) ? 1.f : 0.f;
        float m2 = (ex2 <= last) ? 1.f : 0.f;
        float m3 = (ex3 <= last) ? 1.f : 0.f;
        float my = (ey  <= last) ? 1.f : 0.f;

        ax[0] += m0 * bflo(w0.x); ax[1] += m0 * bfhi(w0.x);
        ax[2] += m0 * bflo(w0.y); ax[3] += m0 * bfhi(w0.y);
        ax[4] += m0 * bflo(w0.z); ax[5] += m0 * bfhi(w0.z);
        ax[6] += m0 * bflo(w0.w); ax[7] += m0 * bfhi(w0.w);

        ax[0] += m1 * bflo(w1.x); ax[1] += m1 * bfhi(w1.x);
        ax[2] += m1 * bflo(w1.y); ax[3] += m1 * bfhi(w1.y);
        ax[4] += m1 * bflo(w1.z); ax[5] += m1 * bfhi(w1.z);
        ax[6] += m1 * bflo(w1.w); ax[7] += m1 * bfhi(w1.w);

        ax[0] += m2 * bflo(w2.x); ax[1] += m2 * bfhi(w2.x);
        ax[2] += m2 * bflo(w2.y); ax[3] += m2 * bfhi(w2.y);
        ax[4] += m2 * bflo(w2.z); ax[5] += m2 * bfhi(w2.z);
        ax[6] += m2 * bflo(w2.w); ax[7] += m2 * bfhi(w2.w);

        ax[0] += m3 * bflo(w3.x); ax[1] += m3 * bfhi(w3.x);
        ax[2] += m3 * bflo(w3.y); ax[3] += m3 * bfhi(w3.y);
        ax[4] += m3 * bflo(w3.z); ax[5] += m3 * bfhi(w3.z);
        ax[6] += m3 * bflo(w3.w); ax[7] += m3 * bfhi(w3.w);

        ay[0] += my * bflo(wy.x); ay[1] += my * bfhi(wy.x);
        ay[2] += my * bflo(wy.y); ay[3] += my * bfhi(wy.y);
        ay[4] += my * bflo(wy.z); ay[5] += my * bfhi(wy.z);
        ay[6] += my * bflo(wy.w); ay[7] += my * bfhi(wy.w);
    }

    #pragma unroll
    for (int m = 16; m <= 32; m <<= 1) {
        #pragma unroll
        for (int i = 0; i < 8; ++i) ax[i] += __shfl_xor(ax[i], m);
    }
    #pragma unroll
    for (int m = 4; m <= 32; m <<= 1) {
        #pragma unroll
        for (int i = 0; i < 8; ++i) ay[i] += __shfl_xor(ay[i], m);
    }

    float sg = 0.9f * di;
    float sl = 0.9f * di + 0.1f / di;   // coefficient on z_row giving the u-space self term

    if (g == 0) {   // lanes 0..15 write x
        uint4 wz = zx[(size_t)row * 16 + sub];
        float c[8] = { bflo(wz.x), bfhi(wz.x), bflo(wz.y), bfhi(wz.y),
                       bflo(wz.z), bfhi(wz.z), bflo(wz.w), bfhi(wz.w) };
        float r[8];
        #pragma unroll
        for (int i = 0; i < 8; ++i) r[i] = sg * ax[i] + sl * c[i];   // u'
        if constexpr (OUTBF) {
            uint4 o;
            o.x = packbf(di * r[0], di * r[1]); o.y = packbf(di * r[2], di * r[3]);
            o.z = packbf(di * r[4], di * r[5]); o.w = packbf(di * r[6], di * r[7]);
            ((uint4*)nx)[(size_t)row * 16 + sub] = o;
        } else {
            float4 a, b;
            a.x = r[0]; a.y = r[1]; a.z = r[2]; a.w = r[3];
            b.x = r[4]; b.y = r[5]; b.z = r[6]; b.w = r[7];
            ((float4*)nx)[(size_t)row * 32 + sub * 2]     = a;
            ((float4*)nx)[(size_t)row * 32 + sub * 2 + 1] = b;
        }
    }
    if (gy == 0) {  // lanes 0..3 write y
        uint4 wz = zy[(size_t)row * 4 + sy];
        float c[8] = { bflo(wz.x), bfhi(wz.x), bflo(wz.y), bfhi(wz.y),
                       bflo(wz.z), bfhi(wz.z), bflo(wz.w), bfhi(wz.w) };
        float r[8];
        #pragma unroll
        for (int i = 0; i < 8; ++i) r[i] = sg * ay[i] + sl * c[i];
        if constexpr (OUTBF) {
            uint4 o;
            o.x = packbf(di * r[0], di * r[1]); o.y = packbf(di * r[2], di * r[3]);
            o.z = packbf(di * r[4], di * r[5]); o.w = packbf(di * r[6], di * r[7]);
            ((uint4*)ny)[(size_t)row * 4 + sy] = o;
        } else {
            float4 a, b;
            a.x = r[0]; a.y = r[1]; a.z = r[2]; a.w = r[3];
            b.x = r[4]; b.y = r[5]; b.z = r[6]; b.w = r[7];
            ((float4*)ny)[(size_t)row * 8 + sy * 2]     = a;
            ((float4*)ny)[(size_t)row * 8 + sy * 2 + 1] = b;
        }
    }
}

extern "C" void kernel_launch(void* const* d_in, const int* in_sizes, int n_in,
                              void* d_out, int out_size, void* d_ws, size_t ws_size,
                              hipStream_t stream) {
    const float* x0  = (const float*)d_in[0];
    const float* y0  = (const float*)d_in[1];
    const void*  raw = d_in[2];

    float* out_x = (float*)d_out;
    float* out_y = out_x + (size_t)NN * 128;

    // ws layout (4-byte words):
    // flag[16] | indeg_rep[8*NPAD] | gbcur[512*16] | bucket_base[512] | rowptr[100112]
    // | dinv[NPAD] | buf[NBKT*CAP2] | dst_sorted[EE] | zxA[N*64] | zxB[N*64]
    // | zyA[N*16] | zyB[N*16]   ~= 78 MB
    int*   flag        = (int*)d_ws;
    int*   indeg_rep   = flag + 16;
    int*   gbcur       = indeg_rep + 8 * NPAD;
    int*   bucket_base = gbcur + 512 * 16;
    int*   rowptr      = bucket_base + 512;
    float* dinv        = (float*)(rowptr + 100112);
    int*   buf         = (int*)(dinv + NPAD);
    int*   dst_sorted  = buf + (size_t)NBKT * CAP2;
    uint4* zxA         = (uint4*)(dst_sorted + EE);
    uint4* zxB         = zxA + (size_t)NN * 16;
    uint4* zyA         = (uint4*)(zxB + (size_t)NN * 16);
    uint4* zyB         = zyA + (size_t)NN * 4;

    const int B = 256;
    const int GW = (NN * 64 + B - 1) / B;   // one wave per row
    const int ZTOT = 8 * NPAD + 512 * 16;

    detect_kernel<<<1, 64, 0, stream>>>((const int*)raw, flag);
    zero_kernel<<<(ZTOT + B - 1) / B, B, 0, stream>>>(indeg_rep, ZTOT);
    passA_kernel<<<(EE + CHUNK - 1) / CHUNK, 256, 0, stream>>>(raw, flag, indeg_rep, gbcur, buf);
    bucket_scan_kernel<<<1, 512, 0, stream>>>(gbcur, bucket_base, rowptr);
    dinv_kernel<<<(NN + B - 1) / B, B, 0, stream>>>(indeg_rep, dinv);
    cast_kernel<<<(NN * 20 + B - 1) / B, B, 0, stream>>>(
        (const float4*)x0, (const float4*)y0, dinv, zxA, zyA);
    passB_kernel<<<NBKT, 256, 0, stream>>>(gbcur, buf, bucket_base, rowptr, dst_sorted);

    // hops 1-3: bf16 z -> bf16 z ; hop 4: bf16 z -> fp32 u (d_out)
    hop_kernel<true><<<GW, B, 0, stream>>>(rowptr, dst_sorted, dinv, zxA, zyA, zxB, zyB);
    hop_kernel<true><<<GW, B, 0, stream>>>(rowptr, dst_sorted, dinv, zxB, zyB, zxA, zyA);
    hop_kernel<true><<<GW, B, 0, stream>>>(rowptr, dst_sorted, dinv, zxA, zyA, zxB, zyB);
    hop_kernel<false><<<GW, B, 0, stream>>>(rowptr, dst_sorted, dinv, zxB, zyB, out_x, out_y);
}